// Round 13
// baseline (394.256 us; speedup 1.0000x reference)
//
#include <hip/hip_runtime.h>

#define BB 4
#define CC 256
#define HH 128
#define WW 128
#define NN (HH*WW)
#define EPSF 1e-10f

// padded NHWC bf16 x: [b][row 0..129][col 0..129][ic 0..255], data at row/col 1..128
#define XR 130
#define XPB ((size_t)XR*XR*CC)

typedef __bf16 bf16x8 __attribute__((ext_vector_type(8)));
typedef float  f32x4  __attribute__((ext_vector_type(4)));

__device__ __forceinline__ float delu_f(float v) {
    // x>0: 10x+1 ; x<=0: exp(10x)
    return v > 0.0f ? fmaf(10.0f, v, 1.0f) : __expf(10.0f * v);
}

// async global->LDS, 16B per lane: LDS dest = base + lane*16 (linear), global src per-lane
__device__ __forceinline__ void gl_lds16(const __bf16* g, __bf16* l) {
    __builtin_amdgcn_global_load_lds(
        (const __attribute__((address_space(1))) void*)g,
        (__attribute__((address_space(3))) void*)l, 16, 0, 0);
}

// ---------------- weight packs, fragment-linear:
// 1x1:  wpk[kb 0..7][ocf 0..15][lane 0..63][e 0..7], lane = lq*16+l15, value = w[ocf*16+l15][kb*32+lq*8+e]
// conv: wcv[t 0..8][kb 0..7][ocf 0..15][lane][e], wd1 folded into t=4
__global__ __launch_bounds__(256) void k_prep(const float* __restrict__ wq,
    const float* __restrict__ wk, const float* __restrict__ wv,
    const float* __restrict__ wd1, const float* __restrict__ wd3,
    __bf16* __restrict__ wqb, __bf16* __restrict__ wkb, __bf16* __restrict__ wvb,
    __bf16* __restrict__ wcv)
{
    int idx = blockIdx.x * 256 + threadIdx.x;   // oc*256+ic
    if (idx >= CC*CC) return;
    const int oc = idx >> 8, ic = idx & 255;
    const int kb = ic >> 5, ocf = oc >> 4;
    const int lane = ((ic >> 3) & 3)*16 + (oc & 15);
    const int e = ic & 7;
    const size_t off = ((size_t)(kb*16 + ocf)*64 + lane)*8 + e;
    wqb[off] = (__bf16)wq[idx];
    wkb[off] = (__bf16)wk[idx];
    wvb[off] = (__bf16)wv[idx];
    float w9[9];
    #pragma unroll
    for (int k=0;k<9;k++) w9[k] = wd3[(size_t)idx*9 + k];
    w9[4] += wd1[idx];
    #pragma unroll
    for (int t=0;t<9;t++) wcv[(size_t)t*CC*CC + off] = (__bf16)w9[t];
}

// ---------------- xpad: NCHW fp32 -> padded NHWC bf16
__global__ __launch_bounds__(256) void k_xpad(const float* __restrict__ x,
                                              __bf16* __restrict__ xpad)
{
    const int xrow = blockIdx.x;            // 0..129
    const int b    = blockIdx.y;
    const int tid  = threadIdx.x;
    const int hr   = xrow - 1;
    const float* xb = x + (size_t)b*CC*NN;
    __bf16* xpb = xpad + (size_t)b*XPB + (size_t)xrow*XR*CC;
    const bool rowok = (hr >= 0 && hr < HH);
    for (int t = tid; t < XR*32; t += 256) {
        int xcol = t % XR, icg = t / XR;
        int wc = xcol - 1;
        bf16x8 v8 = {};
        if (rowok && wc >= 0 && wc < WW) {
            const float* p = xb + (size_t)(icg*8)*NN + hr*WW + wc;
            #pragma unroll
            for (int j=0;j<8;j++) v8[j] = (__bf16)p[(size_t)j*NN];
        }
        *(bf16x8*)&xpb[(size_t)xcol*CC + icg*8] = v8;
    }
}

// ---------------- stage 64n x 256ic tile: xpad(NHWC) -> xs[kq 0..31][n 0..63][ic8] via global_load_lds
__device__ __forceinline__ void stage_tile_async(const __bf16* __restrict__ xrb,
                                                 __bf16* __restrict__ xs,
                                                 int wid, int lane)
{
    #pragma unroll
    for (int j = 0; j < 8; ++j) {
        const int kq = wid + 4*j;
        gl_lds16(xrb + (size_t)lane*CC + kq*8, &xs[(size_t)kq*64*8]);
    }
}

// ---------------- one 64oc x 64n x 256c MFMA GEMM; A from packed wb (L2, coalesced), B from LDS xs
__device__ __forceinline__ void mfma_gemm_l(const __bf16* __restrict__ wb,
                                            const __bf16* __restrict__ xs,
                                            int ocf0, int lane, int l15, int lq,
                                            f32x4 acc[4][4])
{
    #pragma unroll
    for (int kb=0; kb<8; kb++) {
        bf16x8 af[4], bfr[4];
        #pragma unroll
        for (int f=0; f<4; f++)
            af[f] = *(const bf16x8*)&wb[(size_t)((kb*16 + ocf0 + f)*64 + lane)*8];
        #pragma unroll
        for (int nf=0; nf<4; nf++)
            bfr[nf] = *(const bf16x8*)&xs[(size_t)((kb*4 + lq)*64 + nf*16 + l15)*8];
        #pragma unroll
        for (int f=0; f<4; f++)
            #pragma unroll
            for (int nf=0; nf<4; nf++)
                acc[f][nf] = __builtin_amdgcn_mfma_f32_16x16x32_bf16(af[f], bfr[nf], acc[f][nf], 0, 0, 0);
    }
}

// ---------------- q'/k' projections via MFMA + Qs = sum_m delu(q); k' -> kp (bf16)
__global__ __launch_bounds__(256) void k_qk_mfma(const __bf16* __restrict__ xpad,
    const __bf16* __restrict__ wqb, const float* __restrict__ bq,
    const __bf16* __restrict__ wkb, const float* __restrict__ bk,
    __bf16* __restrict__ kp, float* __restrict__ Qs)
{
    __shared__ __bf16 xs[32*64*8];
    __shared__ float Qpart[4][64];
    const int n0 = blockIdx.x * 64;
    const int b  = blockIdx.y;
    const int tid = threadIdx.x;
    const int wid = tid >> 6, lane = tid & 63;
    const int l15 = lane & 15, lq = lane >> 4;
    const int oc_base = wid*64;
    const int h = n0 >> 7, w0 = n0 & 127;
    const __bf16* xrb = xpad + (size_t)b*XPB + ((size_t)(h+1)*XR + w0 + 1)*CC;

    stage_tile_async(xrb, xs, wid, lane);
    __syncthreads();

    // --- Q phase ---
    f32x4 acc[4][4] = {};
    mfma_gemm_l(wqb, xs, wid*4, lane, l15, lq, acc);
    #pragma unroll
    for (int nf=0; nf<4; nf++) {
        float s = 0.0f;
        #pragma unroll
        for (int f=0; f<4; f++)
            #pragma unroll
            for (int r=0; r<4; r++)
                s += delu_f(acc[f][nf][r] + bq[oc_base + f*16 + lq*4 + r]);
        s += __shfl_xor(s, 16);
        s += __shfl_xor(s, 32);
        if (lq == 0) Qpart[wid][nf*16 + l15] = s;
    }
    __syncthreads();
    if (tid < 64)
        Qs[(size_t)b*NN + n0 + tid] = Qpart[0][tid] + Qpart[1][tid] + Qpart[2][tid] + Qpart[3][tid];

    // --- K phase ---
    #pragma unroll
    for (int f=0; f<4; f++)
        #pragma unroll
        for (int nf=0; nf<4; nf++)
            acc[f][nf] = (f32x4){0.f,0.f,0.f,0.f};
    mfma_gemm_l(wkb, xs, wid*4, lane, l15, lq, acc);
    #pragma unroll
    for (int f=0; f<4; f++) {
        #pragma unroll
        for (int r=0; r<4; r++) {
            const int oc = oc_base + f*16 + lq*4 + r;
            const float bias = bk[oc];
            __bf16* kr = kp + ((size_t)b*CC + oc)*NN + n0;
            #pragma unroll
            for (int nf=0; nf<4; nf++)
                kr[nf*16 + l15] = (__bf16)delu_f(acc[f][nf][r] + bias);
        }
    }
}

// ---------------- Esum[b,c] = sum_n Qs[b,n] * k'[b,c,n]
__global__ __launch_bounds__(256) void k_esum(const __bf16* __restrict__ kp,
    const float* __restrict__ Qs, float* __restrict__ Es)
{
    const int c = blockIdx.x & (CC-1), b = blockIdx.x >> 8;
    const int tid = threadIdx.x;
    const bf16x8* kr = (const bf16x8*)(kp + ((size_t)b*CC + c)*NN);
    const float4* qr = (const float4*)(Qs + (size_t)b*NN);
    float s = 0.0f;
    for (int i = tid; i < NN/8; i += 256) {
        bf16x8 kk = kr[i];
        float4 q0 = qr[2*i], q1 = qr[2*i+1];
        s += (float)kk[0]*q0.x + (float)kk[1]*q0.y + (float)kk[2]*q0.z + (float)kk[3]*q0.w
           + (float)kk[4]*q1.x + (float)kk[5]*q1.y + (float)kk[6]*q1.z + (float)kk[7]*q1.w;
    }
    #pragma unroll
    for (int m=1; m<64; m<<=1) s += __shfl_xor(s, m, 64);
    __shared__ float red[4];
    if ((tid & 63) == 0) red[tid >> 6] = s;
    __syncthreads();
    if (tid == 0) Es[b*CC + c] = red[0] + red[1] + red[2] + red[3];
}

// ---------------- v projection via MFMA + in-block denom + attention epilogue
__global__ __launch_bounds__(256) void k_vattn_mfma(const float* __restrict__ x,
    const __bf16* __restrict__ xpad,
    const __bf16* __restrict__ wvb, const float* __restrict__ bv,
    const __bf16* __restrict__ kp, const float* __restrict__ Es,
    const float* __restrict__ gamma, float* __restrict__ out)
{
    __shared__ __bf16 xs[32*64*8];
    __shared__ float Dpart[4][64];
    __shared__ float rn_sh[64];
    const int n0 = blockIdx.x * 64;
    const int b  = blockIdx.y;
    const int tid = threadIdx.x;
    const int wid = tid >> 6, lane = tid & 63;
    const int l15 = lane & 15, lq = lane >> 4;
    const int oc_base = wid*64;
    const int h = n0 >> 7, w0 = n0 & 127;
    const __bf16* xrb = xpad + (size_t)b*XPB + ((size_t)(h+1)*XR + w0 + 1)*CC;

    stage_tile_async(xrb, xs, wid, lane);
    __syncthreads();

    f32x4 acc[4][4] = {};
    mfma_gemm_l(wvb, xs, wid*4, lane, l15, lq, acc);

    // denom partials: sum over this thread's 16 oc rows of Es[oc]*k'[oc][w]
    float dpart[4] = {0.f,0.f,0.f,0.f};
    #pragma unroll
    for (int f=0; f<4; f++) {
        #pragma unroll
        for (int r=0; r<4; r++) {
            const int oc = oc_base + f*16 + lq*4 + r;
            const float e = Es[b*CC + oc];
            const __bf16* kr = kp + ((size_t)b*CC + oc)*NN + n0;
            #pragma unroll
            for (int nf=0; nf<4; nf++)
                dpart[nf] = fmaf(e, (float)kr[nf*16 + l15], dpart[nf]);
        }
    }
    #pragma unroll
    for (int nf=0; nf<4; nf++) {
        dpart[nf] += __shfl_xor(dpart[nf], 16);
        dpart[nf] += __shfl_xor(dpart[nf], 32);
        if (lq == 0) Dpart[wid][nf*16 + l15] = dpart[nf];
    }
    __syncthreads();
    if (tid < 64)
        rn_sh[tid] = 1.0f / (Dpart[0][tid] + Dpart[1][tid] + Dpart[2][tid] + Dpart[3][tid] + EPSF);
    __syncthreads();

    const float g = gamma[0];
    float rv[4];
    #pragma unroll
    for (int nf=0; nf<4; nf++) rv[nf] = rn_sh[nf*16 + l15];
    #pragma unroll
    for (int f=0; f<4; f++) {
        #pragma unroll
        for (int r=0; r<4; r++) {
            const int oc = oc_base + f*16 + lq*4 + r;
            const float eg = Es[b*CC + oc] * g;
            const float bias = bv[oc];
            const __bf16* kr = kp + ((size_t)b*CC + oc)*NN + n0;
            const float* xr  = x  + ((size_t)b*CC + oc)*NN + n0;
            float* orow = out + ((size_t)b*CC + oc)*NN + n0;
            #pragma unroll
            for (int nf=0; nf<4; nf++) {
                const int w = nf*16 + l15;
                orow[w] = fmaf(eg*(float)kr[w]*rv[nf], acc[f][nf][r] + bias, xr[w]);
            }
        }
    }
}

// ---------------- 3x3 conv (+folded 1x1) via MFMA, 512 thr = 8 waves (2 rows x 2 oc x 2 col);
// R9-proven pipelined tap loop per wave; 4 staged xpad rows shared by both row-groups.
__global__ __launch_bounds__(512,4) void k_conv_mfma(const __bf16* __restrict__ xpad,
    const __bf16* __restrict__ wcv, const float* __restrict__ bd1,
    const float* __restrict__ bd3, const float* __restrict__ gamma,
    float* __restrict__ out)
{
    __shared__ __bf16 xs[2][16*132*8];
    // bijective XCD swizzle: nwg=512, 64 per XCD -> contiguous band per XCD
    const int orig = blockIdx.x;
    const int wg   = (orig & 7)*64 + (orig >> 3);
    const int b    = wg >> 7;
    const int rem  = wg & 127;
    const int h0   = (rem >> 1)*2;     // output rows h0, h0+1
    const int ocb  = rem & 1;
    const int tid = threadIdx.x;
    const int wid = tid >> 6, lane = tid & 63;
    const int rr = wid >> 2;                 // 0/1: which output row
    const int wm = (wid >> 1) & 1, wn = wid & 1;
    const int l15 = lane & 15, lq = lane >> 4;
    const int oc_base  = ocb*128 + wm*64;
    const int ocf0     = ocb*8 + wm*4;
    const int col_base = wn*64;
    const int hout = h0 + rr;
    const __bf16* xpb = xpad + (size_t)b*XPB;

    f32x4 acc[4][4] = {};

    // stage icb slice (16 pairs x 130 cols: xpad rows h0..h0+3) into xs[bufsel]:
    // 48 chunk-items over 8 waves
    #define STAGE_CV(bufsel, icb) do {                                          \
        const int ic0_ = (icb)*32;                                              \
        _Pragma("unroll")                                                       \
        for (int j = 0; j < 6; ++j) {                                           \
            const int w_ = wid + 8*j;                                           \
            const int pair_ = w_ / 3, chunk_ = w_ % 3;                          \
            const int r_ = pair_ >> 2, icq_ = pair_ & 3;                        \
            const int col0_ = chunk_ * 64;                                      \
            if (col0_ + lane < XR)                                              \
                gl_lds16(xpb + ((size_t)(h0 + r_)*XR + col0_ + lane)*CC + ic0_ + icq_*8, \
                         &xs[bufsel][(size_t)(pair_*132 + col0_)*8]);           \
        }                                                                       \
    } while (0)

    STAGE_CV(0, 0);
    __syncthreads();

    #pragma unroll 1
    for (int icb = 0; icb < 8; ++icb) {
        const __bf16* xb = xs[icb & 1];
        bf16x8 af2[2][4], br2[2][4];
        // tap-0 af FIRST (before stage -> its vmcnt wait doesn't drain the prefetch)
        #pragma unroll
        for (int f=0; f<4; f++)
            af2[0][f] = *(const bf16x8*)&wcv[(size_t)((icb*16 + ocf0 + f)*64 + lane)*8];
        if (icb < 7) STAGE_CV((icb+1)&1, icb+1);     // async prefetch of next ic-block
        #pragma unroll
        for (int nf=0; nf<4; nf++)
            br2[0][nf] = *(const bf16x8*)&xb[(size_t)(((rr)*4 + lq)*132 + col_base + nf*16 + l15)*8];
        #pragma unroll
        for (int t=0; t<9; ++t) {
            const int cur = t & 1, nxt = cur ^ 1;
            if (t < 8) {
                const int tn = t + 1, kyn = tn/3, kxn = tn%3;
                #pragma unroll
                for (int f=0; f<4; f++)
                    af2[nxt][f] = *(const bf16x8*)&wcv[(size_t)(((tn*8 + icb)*16 + ocf0 + f)*64 + lane)*8];
                #pragma unroll
                for (int nf=0; nf<4; nf++)
                    br2[nxt][nf] = *(const bf16x8*)&xb[(size_t)(((rr + kyn)*4 + lq)*132 + col_base + nf*16 + l15 + kxn)*8];
            }
            __builtin_amdgcn_s_setprio(1);
            #pragma unroll
            for (int f=0; f<4; f++)
                #pragma unroll
                for (int nf=0; nf<4; nf++)
                    acc[f][nf] = __builtin_amdgcn_mfma_f32_16x16x32_bf16(af2[cur][f], br2[cur][nf], acc[f][nf], 0, 0, 0);
            __builtin_amdgcn_s_setprio(0);
        }
        __syncthreads();
    }
    #undef STAGE_CV

    const float g = gamma[0];
    #pragma unroll
    for (int f=0; f<4; f++) {
        #pragma unroll
        for (int r=0; r<4; r++) {
            const int oc = oc_base + f*16 + lq*4 + r;
            const float bias = bd1[oc] + bd3[oc];
            float* orow = out + ((size_t)b*CC + oc)*NN + (size_t)hout*WW;
            #pragma unroll
            for (int nf=0; nf<4; nf++) {
                const int w = col_base + nf*16 + l15;
                orow[w] += g*(acc[f][nf][r] + bias);
            }
        }
    }
}

extern "C" void kernel_launch(void* const* d_in, const int* in_sizes, int n_in,
                              void* d_out, int out_size, void* d_ws, size_t ws_size,
                              hipStream_t stream)
{
    const float* x     = (const float*)d_in[0];
    const float* wq    = (const float*)d_in[1];
    const float* bq    = (const float*)d_in[2];
    const float* wk    = (const float*)d_in[3];
    const float* bk    = (const float*)d_in[4];
    const float* wv    = (const float*)d_in[5];
    const float* bv    = (const float*)d_in[6];
    const float* wd1   = (const float*)d_in[7];
    const float* bd1   = (const float*)d_in[8];
    const float* wd3   = (const float*)d_in[9];
    const float* bd3   = (const float*)d_in[10];
    const float* gamma = (const float*)d_in[11];
    float* out = (float*)d_out;

    __bf16* kp   = (__bf16*)d_ws;                    // B*C*N bf16 (33.5 MB)
    float*  Qs   = (float*)(kp + (size_t)BB*CC*NN);  // B*N
    float*  Es   = Qs + (size_t)BB*NN;               // B*C
    __bf16* wcv  = (__bf16*)(Es + (size_t)BB*CC);    // [9][256][256] bf16, fragment-linear
    __bf16* wqb  = wcv + (size_t)9*CC*CC;            // [256][256] bf16, fragment-linear
    __bf16* wkb  = wqb + (size_t)CC*CC;
    __bf16* wvb  = wkb + (size_t)CC*CC;
    __bf16* xpad = wvb + (size_t)CC*CC;              // [4][130][130][256] bf16 (34.6 MB)

    k_prep      <<<dim3(CC*CC/256), 256, 0, stream>>>(wq, wk, wv, wd1, wd3, wqb, wkb, wvb, wcv);
    k_xpad      <<<dim3(XR, BB), 256, 0, stream>>>(x, xpad);
    k_qk_mfma   <<<dim3(NN/64, BB), 256, 0, stream>>>(xpad, wqb, bq, wkb, bk, kp, Qs);
    k_esum      <<<dim3(BB*CC), 256, 0, stream>>>(kp, Qs, Es);
    k_vattn_mfma<<<dim3(NN/64, BB), 256, 0, stream>>>(x, xpad, wvb, bv, kp, Es, gamma, out);
    k_conv_mfma <<<dim3(2*(HH/2)*BB), 512, 0, stream>>>(xpad, wcv, bd1, bd3, gamma, out);
}

// Round 14
// 199.884 us; speedup vs baseline: 1.9724x; 1.9724x over previous
//
#include <hip/hip_runtime.h>

#define BB 4
#define CC 256
#define HH 128
#define WW 128
#define NN (HH*WW)
#define EPSF 1e-10f

// padded NHWC bf16 x: [b][row 0..129][col 0..129][ic 0..255], data at row/col 1..128
#define XR 130
#define XPB ((size_t)XR*XR*CC)

typedef __bf16 bf16x8 __attribute__((ext_vector_type(8)));
typedef float  f32x4  __attribute__((ext_vector_type(4)));

__device__ __forceinline__ float delu_f(float v) {
    // x>0: 10x+1 ; x<=0: exp(10x)
    return v > 0.0f ? fmaf(10.0f, v, 1.0f) : __expf(10.0f * v);
}

// async global->LDS, 16B per lane: LDS dest = base + lane*16 (linear), global src per-lane
__device__ __forceinline__ void gl_lds16(const __bf16* g, __bf16* l) {
    __builtin_amdgcn_global_load_lds(
        (const __attribute__((address_space(1))) void*)g,
        (__attribute__((address_space(3))) void*)l, 16, 0, 0);
}

// ---------------- weight packs, fragment-linear:
// 1x1:  wpk[kb 0..7][ocf 0..15][lane 0..63][e 0..7], lane = lq*16+l15, value = w[ocf*16+l15][kb*32+lq*8+e]
// conv: wcv[t 0..8][kb 0..7][ocf 0..15][lane][e], wd1 folded into t=4
__global__ __launch_bounds__(256) void k_prep(const float* __restrict__ wq,
    const float* __restrict__ wk, const float* __restrict__ wv,
    const float* __restrict__ wd1, const float* __restrict__ wd3,
    __bf16* __restrict__ wqb, __bf16* __restrict__ wkb, __bf16* __restrict__ wvb,
    __bf16* __restrict__ wcv)
{
    int idx = blockIdx.x * 256 + threadIdx.x;   // oc*256+ic
    if (idx >= CC*CC) return;
    const int oc = idx >> 8, ic = idx & 255;
    const int kb = ic >> 5, ocf = oc >> 4;
    const int lane = ((ic >> 3) & 3)*16 + (oc & 15);
    const int e = ic & 7;
    const size_t off = ((size_t)(kb*16 + ocf)*64 + lane)*8 + e;
    wqb[off] = (__bf16)wq[idx];
    wkb[off] = (__bf16)wk[idx];
    wvb[off] = (__bf16)wv[idx];
    float w9[9];
    #pragma unroll
    for (int k=0;k<9;k++) w9[k] = wd3[(size_t)idx*9 + k];
    w9[4] += wd1[idx];
    #pragma unroll
    for (int t=0;t<9;t++) wcv[(size_t)t*CC*CC + off] = (__bf16)w9[t];
}

// ---------------- xpad: NCHW fp32 -> padded NHWC bf16
__global__ __launch_bounds__(256) void k_xpad(const float* __restrict__ x,
                                              __bf16* __restrict__ xpad)
{
    const int xrow = blockIdx.x;            // 0..129
    const int b    = blockIdx.y;
    const int tid  = threadIdx.x;
    const int hr   = xrow - 1;
    const float* xb = x + (size_t)b*CC*NN;
    __bf16* xpb = xpad + (size_t)b*XPB + (size_t)xrow*XR*CC;
    const bool rowok = (hr >= 0 && hr < HH);
    for (int t = tid; t < XR*32; t += 256) {
        int xcol = t % XR, icg = t / XR;
        int wc = xcol - 1;
        bf16x8 v8 = {};
        if (rowok && wc >= 0 && wc < WW) {
            const float* p = xb + (size_t)(icg*8)*NN + hr*WW + wc;
            #pragma unroll
            for (int j=0;j<8;j++) v8[j] = (__bf16)p[(size_t)j*NN];
        }
        *(bf16x8*)&xpb[(size_t)xcol*CC + icg*8] = v8;
    }
}

// ---------------- stage 64n x 256ic tile: xpad(NHWC) -> xs[kq 0..31][n 0..63][ic8] via global_load_lds
__device__ __forceinline__ void stage_tile_async(const __bf16* __restrict__ xrb,
                                                 __bf16* __restrict__ xs,
                                                 int wid, int lane)
{
    #pragma unroll
    for (int j = 0; j < 8; ++j) {
        const int kq = wid + 4*j;
        gl_lds16(xrb + (size_t)lane*CC + kq*8, &xs[(size_t)kq*64*8]);
    }
}

// ---------------- one 64oc x 64n x 256c MFMA GEMM; A from packed wb (L2, coalesced), B from LDS xs
__device__ __forceinline__ void mfma_gemm_l(const __bf16* __restrict__ wb,
                                            const __bf16* __restrict__ xs,
                                            int ocf0, int lane, int l15, int lq,
                                            f32x4 acc[4][4])
{
    #pragma unroll
    for (int kb=0; kb<8; kb++) {
        bf16x8 af[4], bfr[4];
        #pragma unroll
        for (int f=0; f<4; f++)
            af[f] = *(const bf16x8*)&wb[(size_t)((kb*16 + ocf0 + f)*64 + lane)*8];
        #pragma unroll
        for (int nf=0; nf<4; nf++)
            bfr[nf] = *(const bf16x8*)&xs[(size_t)((kb*4 + lq)*64 + nf*16 + l15)*8];
        #pragma unroll
        for (int f=0; f<4; f++)
            #pragma unroll
            for (int nf=0; nf<4; nf++)
                acc[f][nf] = __builtin_amdgcn_mfma_f32_16x16x32_bf16(af[f], bfr[nf], acc[f][nf], 0, 0, 0);
    }
}

// ---------------- q'/k' projections via MFMA + Qs = sum_m delu(q); k' -> kp (bf16)
__global__ __launch_bounds__(256) void k_qk_mfma(const __bf16* __restrict__ xpad,
    const __bf16* __restrict__ wqb, const float* __restrict__ bq,
    const __bf16* __restrict__ wkb, const float* __restrict__ bk,
    __bf16* __restrict__ kp, float* __restrict__ Qs)
{
    __shared__ __bf16 xs[32*64*8];
    __shared__ float Qpart[4][64];
    const int n0 = blockIdx.x * 64;
    const int b  = blockIdx.y;
    const int tid = threadIdx.x;
    const int wid = tid >> 6, lane = tid & 63;
    const int l15 = lane & 15, lq = lane >> 4;
    const int oc_base = wid*64;
    const int h = n0 >> 7, w0 = n0 & 127;
    const __bf16* xrb = xpad + (size_t)b*XPB + ((size_t)(h+1)*XR + w0 + 1)*CC;

    stage_tile_async(xrb, xs, wid, lane);
    __syncthreads();

    // --- Q phase ---
    f32x4 acc[4][4] = {};
    mfma_gemm_l(wqb, xs, wid*4, lane, l15, lq, acc);
    #pragma unroll
    for (int nf=0; nf<4; nf++) {
        float s = 0.0f;
        #pragma unroll
        for (int f=0; f<4; f++)
            #pragma unroll
            for (int r=0; r<4; r++)
                s += delu_f(acc[f][nf][r] + bq[oc_base + f*16 + lq*4 + r]);
        s += __shfl_xor(s, 16);
        s += __shfl_xor(s, 32);
        if (lq == 0) Qpart[wid][nf*16 + l15] = s;
    }
    __syncthreads();
    if (tid < 64)
        Qs[(size_t)b*NN + n0 + tid] = Qpart[0][tid] + Qpart[1][tid] + Qpart[2][tid] + Qpart[3][tid];

    // --- K phase ---
    #pragma unroll
    for (int f=0; f<4; f++)
        #pragma unroll
        for (int nf=0; nf<4; nf++)
            acc[f][nf] = (f32x4){0.f,0.f,0.f,0.f};
    mfma_gemm_l(wkb, xs, wid*4, lane, l15, lq, acc);
    #pragma unroll
    for (int f=0; f<4; f++) {
        #pragma unroll
        for (int r=0; r<4; r++) {
            const int oc = oc_base + f*16 + lq*4 + r;
            const float bias = bk[oc];
            __bf16* kr = kp + ((size_t)b*CC + oc)*NN + n0;
            #pragma unroll
            for (int nf=0; nf<4; nf++)
                kr[nf*16 + l15] = (__bf16)delu_f(acc[f][nf][r] + bias);
        }
    }
}

// ---------------- Esum[b,c] = sum_n Qs[b,n] * k'[b,c,n]
__global__ __launch_bounds__(256) void k_esum(const __bf16* __restrict__ kp,
    const float* __restrict__ Qs, float* __restrict__ Es)
{
    const int c = blockIdx.x & (CC-1), b = blockIdx.x >> 8;
    const int tid = threadIdx.x;
    const bf16x8* kr = (const bf16x8*)(kp + ((size_t)b*CC + c)*NN);
    const float4* qr = (const float4*)(Qs + (size_t)b*NN);
    float s = 0.0f;
    for (int i = tid; i < NN/8; i += 256) {
        bf16x8 kk = kr[i];
        float4 q0 = qr[2*i], q1 = qr[2*i+1];
        s += (float)kk[0]*q0.x + (float)kk[1]*q0.y + (float)kk[2]*q0.z + (float)kk[3]*q0.w
           + (float)kk[4]*q1.x + (float)kk[5]*q1.y + (float)kk[6]*q1.z + (float)kk[7]*q1.w;
    }
    #pragma unroll
    for (int m=1; m<64; m<<=1) s += __shfl_xor(s, m, 64);
    __shared__ float red[4];
    if ((tid & 63) == 0) red[tid >> 6] = s;
    __syncthreads();
    if (tid == 0) Es[b*CC + c] = red[0] + red[1] + red[2] + red[3];
}

// ---------------- v projection via MFMA + in-block denom + attention epilogue
__global__ __launch_bounds__(256) void k_vattn_mfma(const float* __restrict__ x,
    const __bf16* __restrict__ xpad,
    const __bf16* __restrict__ wvb, const float* __restrict__ bv,
    const __bf16* __restrict__ kp, const float* __restrict__ Es,
    const float* __restrict__ gamma, float* __restrict__ out)
{
    __shared__ __bf16 xs[32*64*8];
    __shared__ float Dpart[4][64];
    __shared__ float rn_sh[64];
    const int n0 = blockIdx.x * 64;
    const int b  = blockIdx.y;
    const int tid = threadIdx.x;
    const int wid = tid >> 6, lane = tid & 63;
    const int l15 = lane & 15, lq = lane >> 4;
    const int oc_base = wid*64;
    const int h = n0 >> 7, w0 = n0 & 127;
    const __bf16* xrb = xpad + (size_t)b*XPB + ((size_t)(h+1)*XR + w0 + 1)*CC;

    stage_tile_async(xrb, xs, wid, lane);
    __syncthreads();

    f32x4 acc[4][4] = {};
    mfma_gemm_l(wvb, xs, wid*4, lane, l15, lq, acc);

    // denom partials: sum over this thread's 16 oc rows of Es[oc]*k'[oc][w]
    float dpart[4] = {0.f,0.f,0.f,0.f};
    #pragma unroll
    for (int f=0; f<4; f++) {
        #pragma unroll
        for (int r=0; r<4; r++) {
            const int oc = oc_base + f*16 + lq*4 + r;
            const float e = Es[b*CC + oc];
            const __bf16* kr = kp + ((size_t)b*CC + oc)*NN + n0;
            #pragma unroll
            for (int nf=0; nf<4; nf++)
                dpart[nf] = fmaf(e, (float)kr[nf*16 + l15], dpart[nf]);
        }
    }
    #pragma unroll
    for (int nf=0; nf<4; nf++) {
        dpart[nf] += __shfl_xor(dpart[nf], 16);
        dpart[nf] += __shfl_xor(dpart[nf], 32);
        if (lq == 0) Dpart[wid][nf*16 + l15] = dpart[nf];
    }
    __syncthreads();
    if (tid < 64)
        rn_sh[tid] = 1.0f / (Dpart[0][tid] + Dpart[1][tid] + Dpart[2][tid] + Dpart[3][tid] + EPSF);
    __syncthreads();

    const float g = gamma[0];
    float rv[4];
    #pragma unroll
    for (int nf=0; nf<4; nf++) rv[nf] = rn_sh[nf*16 + l15];
    #pragma unroll
    for (int f=0; f<4; f++) {
        #pragma unroll
        for (int r=0; r<4; r++) {
            const int oc = oc_base + f*16 + lq*4 + r;
            const float eg = Es[b*CC + oc] * g;
            const float bias = bv[oc];
            const __bf16* kr = kp + ((size_t)b*CC + oc)*NN + n0;
            const float* xr  = x  + ((size_t)b*CC + oc)*NN + n0;
            float* orow = out + ((size_t)b*CC + oc)*NN + n0;
            #pragma unroll
            for (int nf=0; nf<4; nf++) {
                const int w = nf*16 + l15;
                orow[w] = fmaf(eg*(float)kr[w]*rv[nf], acc[f][nf][r] + bias, xr[w]);
            }
        }
    }
}

// ---------------- 3x3 conv (+folded 1x1) via MFMA, af-reuse design:
// 256 thr = 4 waves (wm 0/1 x rr 0/1); wave = 64 oc x 128 cols (one output row);
// block = 128 oc x 128 cols x 2 rows. Single-buffered 4-row stage (33.8 KB).
// af bytes/MFMA halved vs 64x64 waves -> VMEM-return (L1) no longer the wall.
__global__ __launch_bounds__(256,2) void k_conv_mfma(const __bf16* __restrict__ xpad,
    const __bf16* __restrict__ wcv, const float* __restrict__ bd1,
    const float* __restrict__ bd3, const float* __restrict__ gamma,
    float* __restrict__ out)
{
    __shared__ __bf16 xs[16*132*8];
    // bijective XCD swizzle: nwg=512, 64 per XCD -> contiguous band per XCD
    const int orig = blockIdx.x;
    const int wg   = (orig & 7)*64 + (orig >> 3);
    const int b    = wg >> 7;
    const int rem  = wg & 127;
    const int h0   = (rem >> 1)*2;     // output rows h0, h0+1
    const int ocb  = rem & 1;
    const int tid = threadIdx.x;
    const int wid = tid >> 6, lane = tid & 63;
    const int rr = wid >> 1;                 // 0/1: which output row
    const int wm = wid & 1;
    const int l15 = lane & 15, lq = lane >> 4;
    const int oc_base  = ocb*128 + wm*64;
    const int ocf0     = ocb*8 + wm*4;
    const int hout = h0 + rr;
    const __bf16* xpb = xpad + (size_t)b*XPB;

    f32x4 acc[4][8] = {};

    // stage icb slice (16 pairs x 130 cols: xpad rows h0..h0+3) into xs: 48 items over 4 waves
    #define STAGE_CV(icb) do {                                                  \
        const int ic0_ = (icb)*32;                                              \
        _Pragma("unroll")                                                       \
        for (int j = 0; j < 12; ++j) {                                          \
            const int w_ = wid + 4*j;                                           \
            const int pair_ = w_ / 3, chunk_ = w_ % 3;                          \
            const int r_ = pair_ >> 2, icq_ = pair_ & 3;                        \
            const int col0_ = chunk_ * 64;                                      \
            if (col0_ + lane < XR)                                              \
                gl_lds16(xpb + ((size_t)(h0 + r_)*XR + col0_ + lane)*CC + ic0_ + icq_*8, \
                         &xs[(size_t)(pair_*132 + col0_)*8]);                   \
        }                                                                       \
    } while (0)

    #pragma unroll 1
    for (int icb = 0; icb < 8; ++icb) {
        if (icb) __syncthreads();            // all waves done reading xs
        bf16x8 af2[2][4];
        // tap-0 af issued alongside stage; post-stage barrier drains both
        #pragma unroll
        for (int f=0; f<4; f++)
            af2[0][f] = *(const bf16x8*)&wcv[(size_t)((icb*16 + ocf0 + f)*64 + lane)*8];
        STAGE_CV(icb);
        __syncthreads();                     // stage + af2[0] complete
        #pragma unroll
        for (int t=0; t<9; ++t) {
            const int cur = t & 1, nxt = cur ^ 1;
            const int ky = t/3, kx = t%3;
            if (t < 8) {
                const int tn = t + 1;
                #pragma unroll
                for (int f=0; f<4; f++)
                    af2[nxt][f] = *(const bf16x8*)&wcv[(size_t)(((tn*8 + icb)*16 + ocf0 + f)*64 + lane)*8];
            }
            __builtin_amdgcn_s_setprio(1);
            #pragma unroll
            for (int nf=0; nf<8; nf++) {
                bf16x8 br = *(const bf16x8*)&xs[(size_t)(((rr + ky)*4 + lq)*132 + nf*16 + l15 + kx)*8];
                #pragma unroll
                for (int f=0; f<4; f++)
                    acc[f][nf] = __builtin_amdgcn_mfma_f32_16x16x32_bf16(af2[cur][f], br, acc[f][nf], 0, 0, 0);
            }
            __builtin_amdgcn_s_setprio(0);
        }
    }
    #undef STAGE_CV

    const float g = gamma[0];
    #pragma unroll
    for (int f=0; f<4; f++) {
        #pragma unroll
        for (int r=0; r<4; r++) {
            const int oc = oc_base + f*16 + lq*4 + r;
            const float bias = bd1[oc] + bd3[oc];
            float* orow = out + ((size_t)b*CC + oc)*NN + (size_t)hout*WW;
            #pragma unroll
            for (int nf=0; nf<8; nf++) {
                const int w = nf*16 + l15;
                orow[w] += g*(acc[f][nf][r] + bias);
            }
        }
    }
}

extern "C" void kernel_launch(void* const* d_in, const int* in_sizes, int n_in,
                              void* d_out, int out_size, void* d_ws, size_t ws_size,
                              hipStream_t stream)
{
    const float* x     = (const float*)d_in[0];
    const float* wq    = (const float*)d_in[1];
    const float* bq    = (const float*)d_in[2];
    const float* wk    = (const float*)d_in[3];
    const float* bk    = (const float*)d_in[4];
    const float* wv    = (const float*)d_in[5];
    const float* bv    = (const float*)d_in[6];
    const float* wd1   = (const float*)d_in[7];
    const float* bd1   = (const float*)d_in[8];
    const float* wd3   = (const float*)d_in[9];
    const float* bd3   = (const float*)d_in[10];
    const float* gamma = (const float*)d_in[11];
    float* out = (float*)d_out;

    __bf16* kp   = (__bf16*)d_ws;                    // B*C*N bf16 (33.5 MB)
    float*  Qs   = (float*)(kp + (size_t)BB*CC*NN);  // B*N
    float*  Es   = Qs + (size_t)BB*NN;               // B*C
    __bf16* wcv  = (__bf16*)(Es + (size_t)BB*CC);    // [9][256][256] bf16, fragment-linear
    __bf16* wqb  = wcv + (size_t)9*CC*CC;            // [256][256] bf16, fragment-linear
    __bf16* wkb  = wqb + (size_t)CC*CC;
    __bf16* wvb  = wkb + (size_t)CC*CC;
    __bf16* xpad = wvb + (size_t)CC*CC;              // [4][130][130][256] bf16 (34.6 MB)

    k_prep      <<<dim3(CC*CC/256), 256, 0, stream>>>(wq, wk, wv, wd1, wd3, wqb, wkb, wvb, wcv);
    k_xpad      <<<dim3(XR, BB), 256, 0, stream>>>(x, xpad);
    k_qk_mfma   <<<dim3(NN/64, BB), 256, 0, stream>>>(xpad, wqb, bq, wkb, bk, kp, Qs);
    k_esum      <<<dim3(BB*CC), 256, 0, stream>>>(kp, Qs, Es);
    k_vattn_mfma<<<dim3(NN/64, BB), 256, 0, stream>>>(x, xpad, wvb, bv, kp, Es, gamma, out);
    k_conv_mfma <<<dim3(2*(HH/2)*BB), 256, 0, stream>>>(xpad, wcv, bd1, bd3, gamma, out);
}

// Round 15
// 190.813 us; speedup vs baseline: 2.0662x; 1.0475x over previous
//
#include <hip/hip_runtime.h>

#define BB 4
#define CC 256
#define HH 128
#define WW 128
#define NN (HH*WW)
#define EPSF 1e-10f

// padded NHWC bf16 x: [b][row 0..129][col 0..129][ic 0..255], data at row/col 1..128
#define XR 130
#define XPB ((size_t)XR*XR*CC)

typedef __bf16 bf16x8 __attribute__((ext_vector_type(8)));
typedef float  f32x4  __attribute__((ext_vector_type(4)));
typedef float  f32x16 __attribute__((ext_vector_type(16)));

__device__ __forceinline__ float delu_f(float v) {
    // x>0: 10x+1 ; x<=0: exp(10x)
    return v > 0.0f ? fmaf(10.0f, v, 1.0f) : __expf(10.0f * v);
}

// async global->LDS, 16B per lane: LDS dest = base + lane*16 (linear), global src per-lane
__device__ __forceinline__ void gl_lds16(const __bf16* g, __bf16* l) {
    __builtin_amdgcn_global_load_lds(
        (const __attribute__((address_space(1))) void*)g,
        (__attribute__((address_space(3))) void*)l, 16, 0, 0);
}

// ---------------- weight packs, fragment-linear:
// 1x1 (16x16x32 frags): wpk[kb 0..7][ocf 0..15][lane 0..63][e 0..7]
// conv (32x32x16 frags): wcv32[t 0..8][gks 0..15][ocf32 0..7][lane 0..63][e 0..7]
//   lane = khi*32 + (oc&31), gks = ic>>4, khi = (ic>>3)&1, e = ic&7; wd1 folded into t=4
__global__ __launch_bounds__(256) void k_prep(const float* __restrict__ wq,
    const float* __restrict__ wk, const float* __restrict__ wv,
    const float* __restrict__ wd1, const float* __restrict__ wd3,
    __bf16* __restrict__ wqb, __bf16* __restrict__ wkb, __bf16* __restrict__ wvb,
    __bf16* __restrict__ wcv32)
{
    int idx = blockIdx.x * 256 + threadIdx.x;   // oc*256+ic
    if (idx >= CC*CC) return;
    const int oc = idx >> 8, ic = idx & 255;
    const int kb = ic >> 5, ocf = oc >> 4;
    const int lane = ((ic >> 3) & 3)*16 + (oc & 15);
    const int e = ic & 7;
    const size_t off = ((size_t)(kb*16 + ocf)*64 + lane)*8 + e;
    wqb[off] = (__bf16)wq[idx];
    wkb[off] = (__bf16)wk[idx];
    wvb[off] = (__bf16)wv[idx];
    // conv pack for 32x32x16 fragments
    const int ocf32 = oc >> 5;
    const int gks = ic >> 4, khi = (ic >> 3) & 1;
    const int lane32 = khi*32 + (oc & 31);
    const size_t off32 = ((size_t)((gks*8 + ocf32))*64 + lane32)*8 + e;
    float w9[9];
    #pragma unroll
    for (int k=0;k<9;k++) w9[k] = wd3[(size_t)idx*9 + k];
    w9[4] += wd1[idx];
    #pragma unroll
    for (int t=0;t<9;t++) wcv32[(size_t)t*CC*CC + off32] = (__bf16)w9[t];
}

// ---------------- xpad: NCHW fp32 -> padded NHWC bf16
__global__ __launch_bounds__(256) void k_xpad(const float* __restrict__ x,
                                              __bf16* __restrict__ xpad)
{
    const int xrow = blockIdx.x;            // 0..129
    const int b    = blockIdx.y;
    const int tid  = threadIdx.x;
    const int hr   = xrow - 1;
    const float* xb = x + (size_t)b*CC*NN;
    __bf16* xpb = xpad + (size_t)b*XPB + (size_t)xrow*XR*CC;
    const bool rowok = (hr >= 0 && hr < HH);
    for (int t = tid; t < XR*32; t += 256) {
        int xcol = t % XR, icg = t / XR;
        int wc = xcol - 1;
        bf16x8 v8 = {};
        if (rowok && wc >= 0 && wc < WW) {
            const float* p = xb + (size_t)(icg*8)*NN + hr*WW + wc;
            #pragma unroll
            for (int j=0;j<8;j++) v8[j] = (__bf16)p[(size_t)j*NN];
        }
        *(bf16x8*)&xpb[(size_t)xcol*CC + icg*8] = v8;
    }
}

// ---------------- stage 64n x 256ic tile: xpad(NHWC) -> xs[kq 0..31][n 0..63][ic8] via global_load_lds
__device__ __forceinline__ void stage_tile_async(const __bf16* __restrict__ xrb,
                                                 __bf16* __restrict__ xs,
                                                 int wid, int lane)
{
    #pragma unroll
    for (int j = 0; j < 8; ++j) {
        const int kq = wid + 4*j;
        gl_lds16(xrb + (size_t)lane*CC + kq*8, &xs[(size_t)kq*64*8]);
    }
}

// ---------------- one 64oc x 64n x 256c MFMA GEMM; A from packed wb (L2, coalesced), B from LDS xs
__device__ __forceinline__ void mfma_gemm_l(const __bf16* __restrict__ wb,
                                            const __bf16* __restrict__ xs,
                                            int ocf0, int lane, int l15, int lq,
                                            f32x4 acc[4][4])
{
    #pragma unroll
    for (int kb=0; kb<8; kb++) {
        bf16x8 af[4], bfr[4];
        #pragma unroll
        for (int f=0; f<4; f++)
            af[f] = *(const bf16x8*)&wb[(size_t)((kb*16 + ocf0 + f)*64 + lane)*8];
        #pragma unroll
        for (int nf=0; nf<4; nf++)
            bfr[nf] = *(const bf16x8*)&xs[(size_t)((kb*4 + lq)*64 + nf*16 + l15)*8];
        #pragma unroll
        for (int f=0; f<4; f++)
            #pragma unroll
            for (int nf=0; nf<4; nf++)
                acc[f][nf] = __builtin_amdgcn_mfma_f32_16x16x32_bf16(af[f], bfr[nf], acc[f][nf], 0, 0, 0);
    }
}

// ---------------- q'/k' projections via MFMA + Qs = sum_m delu(q); k' -> kp (bf16)
__global__ __launch_bounds__(256) void k_qk_mfma(const __bf16* __restrict__ xpad,
    const __bf16* __restrict__ wqb, const float* __restrict__ bq,
    const __bf16* __restrict__ wkb, const float* __restrict__ bk,
    __bf16* __restrict__ kp, float* __restrict__ Qs)
{
    __shared__ __bf16 xs[32*64*8];
    __shared__ float Qpart[4][64];
    const int n0 = blockIdx.x * 64;
    const int b  = blockIdx.y;
    const int tid = threadIdx.x;
    const int wid = tid >> 6, lane = tid & 63;
    const int l15 = lane & 15, lq = lane >> 4;
    const int oc_base = wid*64;
    const int h = n0 >> 7, w0 = n0 & 127;
    const __bf16* xrb = xpad + (size_t)b*XPB + ((size_t)(h+1)*XR + w0 + 1)*CC;

    stage_tile_async(xrb, xs, wid, lane);
    __syncthreads();

    // --- Q phase ---
    f32x4 acc[4][4] = {};
    mfma_gemm_l(wqb, xs, wid*4, lane, l15, lq, acc);
    #pragma unroll
    for (int nf=0; nf<4; nf++) {
        float s = 0.0f;
        #pragma unroll
        for (int f=0; f<4; f++)
            #pragma unroll
            for (int r=0; r<4; r++)
                s += delu_f(acc[f][nf][r] + bq[oc_base + f*16 + lq*4 + r]);
        s += __shfl_xor(s, 16);
        s += __shfl_xor(s, 32);
        if (lq == 0) Qpart[wid][nf*16 + l15] = s;
    }
    __syncthreads();
    if (tid < 64)
        Qs[(size_t)b*NN + n0 + tid] = Qpart[0][tid] + Qpart[1][tid] + Qpart[2][tid] + Qpart[3][tid];

    // --- K phase ---
    #pragma unroll
    for (int f=0; f<4; f++)
        #pragma unroll
        for (int nf=0; nf<4; nf++)
            acc[f][nf] = (f32x4){0.f,0.f,0.f,0.f};
    mfma_gemm_l(wkb, xs, wid*4, lane, l15, lq, acc);
    #pragma unroll
    for (int f=0; f<4; f++) {
        #pragma unroll
        for (int r=0; r<4; r++) {
            const int oc = oc_base + f*16 + lq*4 + r;
            const float bias = bk[oc];
            __bf16* kr = kp + ((size_t)b*CC + oc)*NN + n0;
            #pragma unroll
            for (int nf=0; nf<4; nf++)
                kr[nf*16 + l15] = (__bf16)delu_f(acc[f][nf][r] + bias);
        }
    }
}

// ---------------- Esum[b,c] = sum_n Qs[b,n] * k'[b,c,n]
__global__ __launch_bounds__(256) void k_esum(const __bf16* __restrict__ kp,
    const float* __restrict__ Qs, float* __restrict__ Es)
{
    const int c = blockIdx.x & (CC-1), b = blockIdx.x >> 8;
    const int tid = threadIdx.x;
    const bf16x8* kr = (const bf16x8*)(kp + ((size_t)b*CC + c)*NN);
    const float4* qr = (const float4*)(Qs + (size_t)b*NN);
    float s = 0.0f;
    for (int i = tid; i < NN/8; i += 256) {
        bf16x8 kk = kr[i];
        float4 q0 = qr[2*i], q1 = qr[2*i+1];
        s += (float)kk[0]*q0.x + (float)kk[1]*q0.y + (float)kk[2]*q0.z + (float)kk[3]*q0.w
           + (float)kk[4]*q1.x + (float)kk[5]*q1.y + (float)kk[6]*q1.z + (float)kk[7]*q1.w;
    }
    #pragma unroll
    for (int m=1; m<64; m<<=1) s += __shfl_xor(s, m, 64);
    __shared__ float red[4];
    if ((tid & 63) == 0) red[tid >> 6] = s;
    __syncthreads();
    if (tid == 0) Es[b*CC + c] = red[0] + red[1] + red[2] + red[3];
}

// ---------------- v projection via MFMA + in-block denom + attention epilogue
__global__ __launch_bounds__(256) void k_vattn_mfma(const float* __restrict__ x,
    const __bf16* __restrict__ xpad,
    const __bf16* __restrict__ wvb, const float* __restrict__ bv,
    const __bf16* __restrict__ kp, const float* __restrict__ Es,
    const float* __restrict__ gamma, float* __restrict__ out)
{
    __shared__ __bf16 xs[32*64*8];
    __shared__ float Dpart[4][64];
    __shared__ float rn_sh[64];
    const int n0 = blockIdx.x * 64;
    const int b  = blockIdx.y;
    const int tid = threadIdx.x;
    const int wid = tid >> 6, lane = tid & 63;
    const int l15 = lane & 15, lq = lane >> 4;
    const int oc_base = wid*64;
    const int h = n0 >> 7, w0 = n0 & 127;
    const __bf16* xrb = xpad + (size_t)b*XPB + ((size_t)(h+1)*XR + w0 + 1)*CC;

    stage_tile_async(xrb, xs, wid, lane);
    __syncthreads();

    f32x4 acc[4][4] = {};
    mfma_gemm_l(wvb, xs, wid*4, lane, l15, lq, acc);

    // denom partials: sum over this thread's 16 oc rows of Es[oc]*k'[oc][w]
    float dpart[4] = {0.f,0.f,0.f,0.f};
    #pragma unroll
    for (int f=0; f<4; f++) {
        #pragma unroll
        for (int r=0; r<4; r++) {
            const int oc = oc_base + f*16 + lq*4 + r;
            const float e = Es[b*CC + oc];
            const __bf16* kr = kp + ((size_t)b*CC + oc)*NN + n0;
            #pragma unroll
            for (int nf=0; nf<4; nf++)
                dpart[nf] = fmaf(e, (float)kr[nf*16 + l15], dpart[nf]);
        }
    }
    #pragma unroll
    for (int nf=0; nf<4; nf++) {
        dpart[nf] += __shfl_xor(dpart[nf], 16);
        dpart[nf] += __shfl_xor(dpart[nf], 32);
        if (lq == 0) Dpart[wid][nf*16 + l15] = dpart[nf];
    }
    __syncthreads();
    if (tid < 64)
        rn_sh[tid] = 1.0f / (Dpart[0][tid] + Dpart[1][tid] + Dpart[2][tid] + Dpart[3][tid] + EPSF);
    __syncthreads();

    const float g = gamma[0];
    float rv[4];
    #pragma unroll
    for (int nf=0; nf<4; nf++) rv[nf] = rn_sh[nf*16 + l15];
    #pragma unroll
    for (int f=0; f<4; f++) {
        #pragma unroll
        for (int r=0; r<4; r++) {
            const int oc = oc_base + f*16 + lq*4 + r;
            const float eg = Es[b*CC + oc] * g;
            const float bias = bv[oc];
            const __bf16* kr = kp + ((size_t)b*CC + oc)*NN + n0;
            const float* xr  = x  + ((size_t)b*CC + oc)*NN + n0;
            float* orow = out + ((size_t)b*CC + oc)*NN + n0;
            #pragma unroll
            for (int nf=0; nf<4; nf++) {
                const int w = nf*16 + l15;
                orow[w] = fmaf(eg*(float)kr[w]*rv[nf], acc[f][nf][r] + bias, xr[w]);
            }
        }
    }
}

// ---------------- 3x3 conv (+folded 1x1) via 32x32x16 MFMA (2x arithmetic intensity):
// block 256 thr = 4 waves; wave = 64 oc (2 ocf32) x 128 cols (4 nf of 32); block = 256 oc x 1 row.
// R9-proven schedule: dbuf LDS stage (3 xpad rows), tap-0 af before STAGE, depth-2 af prefetch.
// A-frag: lane=khi*32+row, e -> k=khi*8+e (packed in wcv32). B-frag: col=lane&31, k=(lane>>5)*8+e.
// C/D: col=lane&31, row=(reg&3)+8*(reg>>2)+4*(lane>>5)  [m74/m101-verified]
__global__ __launch_bounds__(256,2) void k_conv_mfma(const __bf16* __restrict__ xpad,
    const __bf16* __restrict__ wcv32, const float* __restrict__ bd1,
    const float* __restrict__ bd3, const float* __restrict__ gamma,
    float* __restrict__ out)
{
    __shared__ __bf16 xs[2][12*132*8];
    // bijective XCD swizzle: nwg=512, 64 per XCD -> contiguous h-band per XCD
    const int orig = blockIdx.x;
    const int wg   = (orig & 7)*64 + (orig >> 3);
    const int b    = wg >> 7;
    const int h    = wg & 127;
    const int tid = threadIdx.x;
    const int wid = tid >> 6, lane = tid & 63;
    const int l31 = lane & 31, lhi = lane >> 5;
    const int oc_base = wid*64;          // wave covers oc_base..oc_base+63 (ocf32 = wid*2, wid*2+1)
    const __bf16* xpb = xpad + (size_t)b*XPB;

    f32x16 acc[2][4] = {};   // [ocf f][nf], 32 oc x 32 col fragments

    // stage icb slice (12 pairs = 3 xpad rows h..h+2 x 4 icq, 130 cols) into xs[bufsel]
    #define STAGE_CV(bufsel, icb) do {                                          \
        const int ic0_ = (icb)*32;                                              \
        _Pragma("unroll")                                                       \
        for (int j = 0; j < 9; ++j) {                                           \
            const int w_ = wid + 4*j;                                           \
            const int pair_ = w_ / 3, chunk_ = w_ % 3;                          \
            const int r_ = pair_ >> 2, icq_ = pair_ & 3;                        \
            const int col0_ = chunk_ * 64;                                      \
            if (col0_ + lane < XR)                                              \
                gl_lds16(xpb + ((size_t)(h + r_)*XR + col0_ + lane)*CC + ic0_ + icq_*8, \
                         &xs[bufsel][(size_t)(pair_*132 + col0_)*8]);           \
        }                                                                       \
    } while (0)

    // af loads for one tap: [f 0/1][kk 0/1] from wcv32[t][gks=icb*2+kk][ocf32=wid*2+f]
    #define AF_LOAD(dst, t, icb)                                                \
        _Pragma("unroll")                                                       \
        for (int f=0; f<2; f++)                                                 \
            _Pragma("unroll")                                                   \
            for (int kk=0; kk<2; kk++)                                          \
                dst[f*2+kk] = *(const bf16x8*)&wcv32[((size_t)(t)*CC*CC) +      \
                    ((size_t)((((icb)*2 + kk)*8 + wid*2 + f))*64 + lane)*8];

    STAGE_CV(0, 0);
    __syncthreads();

    #pragma unroll 1
    for (int icb = 0; icb < 8; ++icb) {
        const __bf16* xb = xs[icb & 1];
        bf16x8 af2[2][4];
        // tap-0 af FIRST (before stage -> its vmcnt wait doesn't drain the prefetch)
        AF_LOAD(af2[0], 0, icb);
        if (icb < 7) STAGE_CV((icb+1)&1, icb+1);     // async prefetch of next ic-block
        #pragma unroll
        for (int t=0; t<9; ++t) {
            const int cur = t & 1, nxt = cur ^ 1;
            const int ky = t/3, kx = t%3;
            if (t < 8) { AF_LOAD(af2[nxt], t+1, icb); }
            __builtin_amdgcn_s_setprio(1);
            #pragma unroll
            for (int kk=0; kk<2; kk++) {
                #pragma unroll
                for (int nf=0; nf<4; nf++) {
                    // B-frag: pair = ky*4 + kk*2 + lhi; col = nf*32 + l31 + kx
                    bf16x8 br = *(const bf16x8*)&xs[icb & 1][
                        (size_t)((ky*4 + kk*2 + lhi)*132 + nf*32 + l31 + kx)*8];
                    #pragma unroll
                    for (int f=0; f<2; f++)
                        acc[f][nf] = __builtin_amdgcn_mfma_f32_32x32x16_bf16(
                            af2[cur][f*2+kk], br, acc[f][nf], 0, 0, 0);
                }
            }
            __builtin_amdgcn_s_setprio(0);
        }
        __syncthreads();
    }
    #undef STAGE_CV
    #undef AF_LOAD

    const float g = gamma[0];
    #pragma unroll
    for (int f=0; f<2; f++) {
        #pragma unroll
        for (int reg=0; reg<16; reg++) {
            const int row = (reg & 3) + 8*(reg >> 2) + 4*lhi;
            const int oc = oc_base + f*32 + row;
            const float bias = bd1[oc] + bd3[oc];
            float* orow = out + ((size_t)b*CC + oc)*NN + (size_t)h*WW;
            #pragma unroll
            for (int nf=0; nf<4; nf++) {
                const int w = nf*32 + l31;
                orow[w] += g*(acc[f][nf][reg] + bias);
            }
        }
    }
}

extern "C" void kernel_launch(void* const* d_in, const int* in_sizes, int n_in,
                              void* d_out, int out_size, void* d_ws, size_t ws_size,
                              hipStream_t stream)
{
    const float* x     = (const float*)d_in[0];
    const float* wq    = (const float*)d_in[1];
    const float* bq    = (const float*)d_in[2];
    const float* wk    = (const float*)d_in[3];
    const float* bk    = (const float*)d_in[4];
    const float* wv    = (const float*)d_in[5];
    const float* bv    = (const float*)d_in[6];
    const float* wd1   = (const float*)d_in[7];
    const float* bd1   = (const float*)d_in[8];
    const float* wd3   = (const float*)d_in[9];
    const float* bd3   = (const float*)d_in[10];
    const float* gamma = (const float*)d_in[11];
    float* out = (float*)d_out;

    __bf16* kp    = (__bf16*)d_ws;                    // B*C*N bf16 (33.5 MB)
    float*  Qs    = (float*)(kp + (size_t)BB*CC*NN);  // B*N
    float*  Es    = Qs + (size_t)BB*NN;               // B*C
    __bf16* wcv32 = (__bf16*)(Es + (size_t)BB*CC);    // [9][256][256] bf16, 32x32-fragment-linear
    __bf16* wqb   = wcv32 + (size_t)9*CC*CC;          // [256][256] bf16, fragment-linear
    __bf16* wkb   = wqb + (size_t)CC*CC;
    __bf16* wvb   = wkb + (size_t)CC*CC;
    __bf16* xpad  = wvb + (size_t)CC*CC;              // [4][130][130][256] bf16 (34.6 MB)

    k_prep      <<<dim3(CC*CC/256), 256, 0, stream>>>(wq, wk, wv, wd1, wd3, wqb, wkb, wvb, wcv32);
    k_xpad      <<<dim3(XR, BB), 256, 0, stream>>>(x, xpad);
    k_qk_mfma   <<<dim3(NN/64, BB), 256, 0, stream>>>(xpad, wqb, bq, wkb, bk, kp, Qs);
    k_esum      <<<dim3(BB*CC), 256, 0, stream>>>(kp, Qs, Es);
    k_vattn_mfma<<<dim3(NN/64, BB), 256, 0, stream>>>(x, xpad, wvb, bv, kp, Es, gamma, out);
    k_conv_mfma <<<dim3(HH*BB), 256, 0, stream>>>(xpad, wcv32, bd1, bd3, gamma, out);
}